// Round 1
// baseline (129.736 us; speedup 1.0000x reference)
//
#include <hip/hip_runtime.h>

// LIF neuron forward scan.
// x: (N, T, D) fp32, row-major. For fixed (n, d): v = v*0.5 + x[t];
// spike = (v - 1 >= 0); v -= spike. Output spikes (N, T, D) fp32.
//
// Parallelism: serial in T (carry v), independent across N*D.
// One thread per float4 of D; t-loop unrolled 4-wide so 4 independent
// 16B loads are in flight per wave (memory-bound, HBM roofline ~81us).

constexpr int T_STEPS = 128;
constexpr int D_DIM   = 32768;
constexpr int D4      = D_DIM / 4;   // 8192 float4 per row
constexpr int LOG2_D4 = 13;

__device__ __forceinline__ float lif_step(float& v, float xin) {
    // v*0.5f is exact, so FMA contraction cannot change the result vs numpy.
    v = v * 0.5f + xin;
    float u = v - 1.0f;              // matches reference: spike = 1[(v - V_TH) >= 0]
    bool s = (u >= 0.0f);
    v = s ? u : v;                   // soft reset: v - spike*V_TH == u when spiking
    return s ? 1.0f : 0.0f;
}

__device__ __forceinline__ float4 lif_step4(float4& v, const float4 xv) {
    float4 sp;
    sp.x = lif_step(v.x, xv.x);
    sp.y = lif_step(v.y, xv.y);
    sp.z = lif_step(v.z, xv.z);
    sp.w = lif_step(v.w, xv.w);
    return sp;
}

__global__ __launch_bounds__(256) void lif_fwd(const float4* __restrict__ x,
                                               float4* __restrict__ out,
                                               int nd4) {
    int idx = blockIdx.x * blockDim.x + threadIdx.x;
    if (idx >= nd4) return;

    int n  = idx >> LOG2_D4;
    int d4 = idx & (D4 - 1);
    size_t base = (size_t)n * T_STEPS * D4 + (size_t)d4;

    const float4* xp = x   + base;
    float4*       op = out + base;

    float4 v = make_float4(0.f, 0.f, 0.f, 0.f);

    // 4-wide manual unroll: 4 independent loads issue before the dependent
    // compute chain; keeps ~4 KB/wave of HBM traffic in flight.
    for (int tb = 0; tb < T_STEPS; tb += 4) {
        const float4 x0 = xp[(size_t)(tb + 0) * D4];
        const float4 x1 = xp[(size_t)(tb + 1) * D4];
        const float4 x2 = xp[(size_t)(tb + 2) * D4];
        const float4 x3 = xp[(size_t)(tb + 3) * D4];

        float4 s0 = lif_step4(v, x0);
        float4 s1 = lif_step4(v, x1);
        float4 s2 = lif_step4(v, x2);
        float4 s3 = lif_step4(v, x3);

        op[(size_t)(tb + 0) * D4] = s0;
        op[(size_t)(tb + 1) * D4] = s1;
        op[(size_t)(tb + 2) * D4] = s2;
        op[(size_t)(tb + 3) * D4] = s3;
    }
}

extern "C" void kernel_launch(void* const* d_in, const int* in_sizes, int n_in,
                              void* d_out, int out_size, void* d_ws, size_t ws_size,
                              hipStream_t stream) {
    const float4* x   = (const float4*)d_in[0];
    float4*       out = (float4*)d_out;

    // in_sizes[0] = N*T*D; threads = N*D/4
    int nd4 = in_sizes[0] / (T_STEPS * 4);

    int block = 256;
    int grid  = (nd4 + block - 1) / block;   // 512 blocks for N=16
    lif_fwd<<<grid, block, 0, stream>>>(x, out, nd4);
}

// Round 3
// 117.346 us; speedup vs baseline: 1.1056x; 1.1056x over previous
//
#include <hip/hip_runtime.h>

// LIF neuron forward scan, round 3: software-pipelined, non-temporal.
// (round 2 failed to compile: nontemporal builtins reject HIP_vector_type;
//  use a native clang ext_vector float4 instead.)
//
// x: (N=16, T=128, D=32768) fp32. Per (n,d): v = v*0.5 + x[t];
// spike = (v-1 >= 0); v -= spike (soft reset). Out: spikes, same shape.
//
// Memory-bound: 256 MB read + 256 MB write, zero reuse -> roofline ~80 us
// at the ~6.9 TB/s this chip's memset achieves. Round 1 (129.7 us, 4.1 TB/s)
// exposed HBM read latency. Fix:
//  - UNROLL=8 t-steps/group (8 KB of reads in flight per wave)
//  - explicit prefetch: issue group g+1 loads BEFORE computing group g
//  - non-temporal loads/stores (no reuse; 512 MB total > 256 MB L3)

typedef float f4 __attribute__((ext_vector_type(4)));

constexpr int T_STEPS = 128;
constexpr int D_DIM   = 32768;
constexpr int D4      = D_DIM / 4;         // 8192 f4 per (n,t) row
constexpr int LOG2_D4 = 13;
constexpr int UNROLL  = 8;                 // t-steps per pipelined group
constexpr int NGROUPS = T_STEPS / UNROLL;  // 16

__device__ __forceinline__ float lif_step(float& v, float xin) {
    // v*0.5f is exact (exponent decrement): result matches numpy bit-for-bit
    // regardless of FMA contraction.
    v = v * 0.5f + xin;
    float u = v - 1.0f;                // reference: spike = 1[(v - V_TH) >= 0]
    bool s = (u >= 0.0f);
    v = s ? u : v;                     // soft reset == u exactly when spiking
    return s ? 1.0f : 0.0f;
}

__device__ __forceinline__ f4 lif_step4(f4& v, const f4 xv) {
    f4 sp;
    float t;
    t = v.x; sp.x = lif_step(t, xv.x); v.x = t;
    t = v.y; sp.y = lif_step(t, xv.y); v.y = t;
    t = v.z; sp.z = lif_step(t, xv.z); v.z = t;
    t = v.w; sp.w = lif_step(t, xv.w); v.w = t;
    return sp;
}

__global__ __launch_bounds__(256) void lif_fwd(const f4* __restrict__ x,
                                               f4* __restrict__ out,
                                               int nd4) {
    int idx = blockIdx.x * blockDim.x + threadIdx.x;
    if (idx >= nd4) return;

    int n  = idx >> LOG2_D4;
    int d4 = idx & (D4 - 1);
    size_t base = (size_t)n * T_STEPS * D4 + (size_t)d4;

    const f4* xp = x   + base;
    f4*       op = out + base;

    f4 v = (f4)(0.0f);

    f4 cur[UNROLL], nxt[UNROLL];   // compile-time indices only (no scratch)

    // prologue: load group 0
#pragma unroll
    for (int i = 0; i < UNROLL; ++i)
        cur[i] = __builtin_nontemporal_load(&xp[(size_t)i * D4]);

    for (int g = 1; g < NGROUPS; ++g) {
        const size_t gbase = (size_t)g * UNROLL * D4;
        // issue next group's loads FIRST: they stay in flight while we wait
        // on (and compute from) the current group.
#pragma unroll
        for (int i = 0; i < UNROLL; ++i)
            nxt[i] = __builtin_nontemporal_load(&xp[gbase + (size_t)i * D4]);

        const size_t obase = (size_t)(g - 1) * UNROLL * D4;
#pragma unroll
        for (int i = 0; i < UNROLL; ++i) {
            f4 s = lif_step4(v, cur[i]);
            __builtin_nontemporal_store(s, &op[obase + (size_t)i * D4]);
        }
#pragma unroll
        for (int i = 0; i < UNROLL; ++i)
            cur[i] = nxt[i];
    }

    // epilogue: last group
    const size_t obase = (size_t)(NGROUPS - 1) * UNROLL * D4;
#pragma unroll
    for (int i = 0; i < UNROLL; ++i) {
        f4 s = lif_step4(v, cur[i]);
        __builtin_nontemporal_store(s, &op[obase + (size_t)i * D4]);
    }
}

extern "C" void kernel_launch(void* const* d_in, const int* in_sizes, int n_in,
                              void* d_out, int out_size, void* d_ws, size_t ws_size,
                              hipStream_t stream) {
    const f4* x   = (const f4*)d_in[0];
    f4*       out = (f4*)d_out;

    int nd4 = in_sizes[0] / (T_STEPS * 4);   // N*D/4 = 131072 threads

    int block = 256;
    int grid  = (nd4 + block - 1) / block;   // 512 blocks
    lif_fwd<<<grid, block, 0, stream>>>(x, out, nd4);
}

// Round 4
// 101.740 us; speedup vs baseline: 1.2752x; 1.1534x over previous
//
#include <hip/hip_runtime.h>

// LIF neuron forward scan, round 4: max-TLP scalar variant.
//
// x: (N=16, T=128, D=32768) fp32. Per (n,d): v = v*0.5 + x[t];
// spike = (v-1 >= 0); v -= spike (soft reset). Out: spikes, same shape.
//
// Round 3 (float4/thread, 2 waves/SIMD, prefetch8+NT) = 117.3 us = 73% of
// the 6.3 TB/s copy ceiling. Hypothesis: wave-level TLP (2/SIMD) too low to
// smooth the bursty issue pattern, and each wave's 8 prefetch loads sit at
// 128 KB stride (same HBM channel bits) -> per-wave channel concentration.
// This round: 1 scalar column per thread -> 524,288 threads, 2048 blocks,
// 8 waves/SIMD (4x TLP, 4x channel-stream diversity per CU). Loads are
// 256 B/wave-instr, still perfectly coalesced; VMEM issue rate is trivial.
// __launch_bounds__(256,8) caps VGPRs at 64 so all 8 waves/SIMD fit.

constexpr int T_STEPS = 128;
constexpr int D_DIM   = 32768;
constexpr int LOG2_D  = 15;
constexpr int UNROLL  = 8;                 // t-steps per pipelined group
constexpr int NGROUPS = T_STEPS / UNROLL;  // 16

__device__ __forceinline__ float lif_step(float& v, float xin) {
    // v*0.5f is exact (exponent decrement): result matches numpy bit-for-bit
    // regardless of FMA contraction.
    v = v * 0.5f + xin;
    float u = v - 1.0f;                // reference: spike = 1[(v - V_TH) >= 0]
    bool s = (u >= 0.0f);
    v = s ? u : v;                     // soft reset == u exactly when spiking
    return s ? 1.0f : 0.0f;
}

__global__ __launch_bounds__(256, 8) void lif_fwd(const float* __restrict__ x,
                                                  float* __restrict__ out,
                                                  int nd) {
    int idx = blockIdx.x * blockDim.x + threadIdx.x;
    if (idx >= nd) return;

    int n = idx >> LOG2_D;
    int d = idx & (D_DIM - 1);
    size_t base = (size_t)n * T_STEPS * D_DIM + (size_t)d;

    const float* xp = x   + base;
    float*       op = out + base;

    float v = 0.0f;
    float cur[UNROLL], nxt[UNROLL];    // compile-time indices only

    // prologue: load group 0
#pragma unroll
    for (int i = 0; i < UNROLL; ++i)
        cur[i] = __builtin_nontemporal_load(&xp[(size_t)i * D_DIM]);

    for (int g = 1; g < NGROUPS; ++g) {
        const size_t gbase = (size_t)g * UNROLL * D_DIM;
        // issue next group's loads FIRST; they stay in flight while we
        // wait on / compute from the current group.
#pragma unroll
        for (int i = 0; i < UNROLL; ++i)
            nxt[i] = __builtin_nontemporal_load(&xp[gbase + (size_t)i * D_DIM]);

        const size_t obase = (size_t)(g - 1) * UNROLL * D_DIM;
#pragma unroll
        for (int i = 0; i < UNROLL; ++i) {
            float s = lif_step(v, cur[i]);
            __builtin_nontemporal_store(s, &op[obase + (size_t)i * D_DIM]);
        }
#pragma unroll
        for (int i = 0; i < UNROLL; ++i)
            cur[i] = nxt[i];
    }

    // epilogue: last group
    const size_t obase = (size_t)(NGROUPS - 1) * UNROLL * D_DIM;
#pragma unroll
    for (int i = 0; i < UNROLL; ++i) {
        float s = lif_step(v, cur[i]);
        __builtin_nontemporal_store(s, &op[obase + (size_t)i * D_DIM]);
    }
}

extern "C" void kernel_launch(void* const* d_in, const int* in_sizes, int n_in,
                              void* d_out, int out_size, void* d_ws, size_t ws_size,
                              hipStream_t stream) {
    const float* x   = (const float*)d_in[0];
    float*       out = (float*)d_out;

    int nd = in_sizes[0] / T_STEPS;          // N*D = 524288 threads

    int block = 256;
    int grid  = (nd + block - 1) / block;    // 2048 blocks
    lif_fwd<<<grid, block, 0, stream>>>(x, out, nd);
}